// Round 9
// baseline (351.751 us; speedup 1.0000x reference)
//
#include <hip/hip_runtime.h>
#include <hip/hip_bf16.h>

// Attention4D MI355X round 9:
//  k_attn2: merged phase1+2 (th1 mix + bias applied in registers straight
//  from MFMA results - no LDS round trip, one less barrier, no cvt churn),
//  SROW 232->224 (31.8KB LDS -> 5 blocks/CU). Keeps XCD-affinity swizzle.
// B=64, DIM=384, N=196 (14x14), NH=8, KD=32, DV=128.

#define RES   14
#define NSP   196
#define NHD   8
#define KDIM  32
#define DVV   128
#define DIM   384
#define NQK   256
#define SCALE 0.17677669529663687f
#define SROW  224    // LDS score row stride (u16); 448B ≡ bank16: 2-way, free
#define NSTRIP 25    // ceil(196/8)

typedef __attribute__((ext_vector_type(8))) short bf16x8;
typedef __attribute__((ext_vector_type(4))) float f32x4;
typedef unsigned short u16;
typedef unsigned int u32;

__device__ __forceinline__ u16 f2b(float f) {
    union { __hip_bfloat16 b; u16 u; } c; c.b = __float2bfloat16(f); return c.u;
}
__device__ __forceinline__ float b2f(u16 u) {
    union { __hip_bfloat16 b; u16 u; } c; c.u = u; return __bfloat162float(c.b);
}

// async global->LDS, 16B per lane; LDS dest = wave-uniform base + lane*16
__device__ __forceinline__ void gld16(const void* g, void* l) {
    __builtin_amdgcn_global_load_lds(
        (__attribute__((address_space(1))) void*)(unsigned long long)(const char*)g,
        (__attribute__((address_space(3))) void*)l, 16, 0, 0);
}

// ---- shared 128x128 bf16 MFMA GEMM core (m97 structure) ----
__device__ __forceinline__ void gemm128(const char* Aseg, long rbA,
                                        const char* Bseg, long rbB, int kIters,
                                        u16* A_lds, u16* B_lds, f32x4 acc[4][4])
{
    const int tid  = threadIdx.x;
    const int wid  = tid >> 6;
    const int lane = tid & 63;
    const int lrow = lane >> 2;
    const int lcb  = (lane & 3) << 4;
    const int r0   = wid * 32;
    const int wm   = (wid & 1) * 64, wn = (wid >> 1) * 64;
    const int l15  = lane & 15, lq8 = (lane >> 4) * 8;

    #pragma unroll
    for (int i = 0; i < 4; ++i)
        #pragma unroll
        for (int j = 0; j < 4; ++j) acc[i][j] = (f32x4){0.f, 0.f, 0.f, 0.f};

    const char* ap0 = Aseg + (long)(r0 + lrow) * rbA + lcb;
    const char* ap1 = ap0 + 16 * rbA;
    const char* bp0 = Bseg + (long)(r0 + lrow) * rbB + lcb;
    const char* bp1 = bp0 + 16 * rbB;
    u16* la0 = A_lds + r0 * 32;
    u16* la1 = A_lds + (r0 + 16) * 32;
    u16* lb0 = B_lds + r0 * 32;
    u16* lb1 = B_lds + (r0 + 16) * 32;

    for (int kk = 0; kk < kIters; ++kk) {
        gld16(ap0, la0); gld16(ap1, la1);
        gld16(bp0, lb0); gld16(bp1, lb1);
        ap0 += 64; ap1 += 64; bp0 += 64; bp1 += 64;
        __syncthreads();
        bf16x8 af[4], bfr[4];
        #pragma unroll
        for (int i = 0; i < 4; ++i)
            af[i] = *(const bf16x8*)&A_lds[(wm + i * 16 + l15) * 32 + lq8];
        #pragma unroll
        for (int j = 0; j < 4; ++j)
            bfr[j] = *(const bf16x8*)&B_lds[(wn + j * 16 + l15) * 32 + lq8];
        #pragma unroll
        for (int i = 0; i < 4; ++i)
            #pragma unroll
            for (int j = 0; j < 4; ++j)
                acc[i][j] = __builtin_amdgcn_mfma_f32_16x16x32_bf16(
                    af[i], bfr[j], acc[i][j], 0, 0, 0);
        __syncthreads();
    }
}

// ---------------- prep: weights fp32 -> bf16, biasmix, wpack ----------------
__global__ __launch_bounds__(256) void k_prep_w(
    const float* __restrict__ qw, const float* __restrict__ kw,
    const float* __restrict__ vw, const float* __restrict__ pw,
    const float* __restrict__ th1w, const float* __restrict__ th1b,
    const float* __restrict__ bias_seg, const float* __restrict__ vlw,
    u16* __restrict__ wqkv, u16* __restrict__ pwb, float* __restrict__ biasmix,
    u16* __restrict__ wpack)
{
    int i = blockIdx.x * 256 + threadIdx.x;
    if (i < 98304)       wqkv[i] = f2b(qw[i]);
    else if (i < 196608) wqkv[i] = f2b(kw[i - 98304]);
    else if (i < 589824) wqkv[i] = f2b(vw[i - 196608]);
    else if (i < 983040) pwb[i - 589824] = f2b(pw[i - 589824]);
    else if (i < 984608) {
        int i2 = i - 983040;
        int hh = i2 / NSP, off = i2 - hh * NSP;
        float a = th1b[hh];
        #pragma unroll
        for (int g = 0; g < 8; ++g) a += th1w[hh * 8 + g] * bias_seg[g * NSP + off];
        biasmix[i2] = a;
    } else if (i < 993824) {
        int i2 = i - 984608;          // wpack[g*72 + tap*8 + t] = vlw[(g*8+t)*9+tap]
        int g = i2 / 72, r = i2 - g * 72;
        int tap = r >> 3, t = r & 7;
        wpack[i2] = f2b(vlw[(g * 8 + t) * 9 + tap]);
    }
}

// ---------------- prep: x (b,c,n) fp32 -> xb (b*n, c) bf16 ----------------
__global__ __launch_bounds__(256) void k_prep_x(
    const float* __restrict__ x, u16* __restrict__ xb)
{
    __shared__ float t[32][33];
    const int b = blockIdx.z, c0 = blockIdx.y * 32, n0 = blockIdx.x * 32;
    const int tx = threadIdx.x & 31, ty = threadIdx.x >> 5;
    #pragma unroll
    for (int l = 0; l < 4; ++l) {
        int c = c0 + ty + 8 * l, n = n0 + tx;
        t[ty + 8 * l][tx] = (n < NSP) ? x[((long)b * DIM + c) * NSP + n] : 0.f;
    }
    __syncthreads();
    #pragma unroll
    for (int l = 0; l < 4; ++l) {
        int n = n0 + ty + 8 * l, c = c0 + tx;
        if (n < NSP) xb[((long)b * NSP + n) * DIM + c] = f2b(t[tx][ty + 8 * l]);
    }
}

// ---------------- K1: QKV projection (MFMA) ----------------
__global__ __launch_bounds__(256) void k_qkv(
    const u16* __restrict__ xb, const u16* __restrict__ wqkv,
    const float* __restrict__ qb, const float* __restrict__ kb,
    const float* __restrict__ vb,
    u16* __restrict__ qt, u16* __restrict__ kb16, u16* __restrict__ vt)
{
    __shared__ u16 A_lds[4096], B_lds[4096];
    const int m0 = blockIdx.x * 128, oc0 = blockIdx.y * 128;
    f32x4 acc[4][4];
    gemm128((const char*)xb + (long)m0 * 768, 768,
            (const char*)wqkv + (long)oc0 * 768, 768, 12, A_lds, B_lds, acc);

    const int tid = threadIdx.x, wid = tid >> 6, lane = tid & 63;
    const int wm = (wid & 1) * 64, wn = (wid >> 1) * 64;
    const int col = lane & 15, quad = lane >> 4;
    #pragma unroll
    for (int i = 0; i < 4; ++i) {
        #pragma unroll
        for (int j = 0; j < 4; ++j) {
            #pragma unroll
            for (int r = 0; r < 4; ++r) {
                int m  = m0 + wm + i * 16 + quad * 4 + r;
                int oc = oc0 + wn + j * 16 + col;
                int b = m / NSP, n = m - b * NSP;
                float v = acc[i][j][r];
                if (oc < 256) {
                    qt[(long)m * NQK + oc] = f2b(v + qb[oc]);
                } else if (oc < 512) {
                    int o = oc - 256;
                    kb16[(long)m * NQK + o] = f2b(v + kb[o]);
                } else {
                    int o = oc - 512, h = o >> 7, d = o & 127;
                    vt[(((long)b * NHD + h) * NSP + n) * DVV + d] = f2b(v + vb[o]);
                }
            }
        }
    }
}

// ---------------- prep: vt -> vtT (bh, d, m) rows padded to 224 ----------
__global__ __launch_bounds__(256) void k_vtT(
    const u16* __restrict__ vt, u16* __restrict__ vtT)
{
    __shared__ u16 t[32][33];
    const int bh = blockIdx.z, d0 = blockIdx.y * 32, n0 = blockIdx.x * 32;
    const int tx = threadIdx.x & 31, ty = threadIdx.x >> 5;
    #pragma unroll
    for (int l = 0; l < 4; ++l) {
        int n = n0 + ty + 8 * l, d = d0 + tx;
        t[ty + 8 * l][tx] = (n < NSP) ? vt[((long)bh * NSP + n) * DVV + d] : (u16)0;
    }
    __syncthreads();
    #pragma unroll
    for (int l = 0; l < 4; ++l) {
        int d = d0 + ty + 8 * l, m = n0 + tx;
        vtT[((long)bh * DVV + d) * 224 + m] = t[tx][ty + 8 * l];
    }
}

// ---------------- K2: depthwise 3x3 conv, vectorized over 8 d ----------------
__global__ __launch_bounds__(256) void k_dwconv(
    const u16* __restrict__ vt, const u16* __restrict__ wpack,
    const float* __restrict__ vlb, u16* __restrict__ vlt)
{
    const int tid = threadIdx.x;
    const int dg = tid & 15;                 // d0 = dg*8
    const int nl = tid >> 4;                 // 16 n per block
    const int bh = blockIdx.y;
    const int n  = blockIdx.x * 16 + nl;
    if (n >= NSP) return;
    const int d0 = dg * 8;
    const int h  = bh & 7;
    const int y = n / RES, xx = n - y * RES;
    const long plane = (long)bh * NSP * DVV;
    float acc[8];
    #pragma unroll
    for (int t = 0; t < 8; ++t) acc[t] = vlb[h * DVV + d0 + t];
    const u16* wb = wpack + (h * 16 + dg) * 72;
    #pragma unroll
    for (int dy = -1; dy <= 1; ++dy) {
        int yy = y + dy;
        if (yy < 0 || yy >= RES) continue;
        #pragma unroll
        for (int dx = -1; dx <= 1; ++dx) {
            int xn = xx + dx;
            if (xn < 0 || xn >= RES) continue;
            int tap = (dy + 1) * 3 + dx + 1;
            bf16x8 v  = *(const bf16x8*)&vt[plane + (yy * RES + xn) * DVV + d0];
            bf16x8 wv = *(const bf16x8*)&wb[tap * 8];
            #pragma unroll
            for (int t = 0; t < 8; ++t)
                acc[t] += b2f((u16)wv[t]) * b2f((u16)v[t]);
        }
    }
    bf16x8 r;
    #pragma unroll
    for (int t = 0; t < 8; ++t) r[t] = (short)f2b(acc[t]);
    *(bf16x8*)&vlt[plane + (long)n * DVV + d0] = r;
}

// ---------------- K3: fused attention middle, 8-row strips ----------------
// grid 1600: xcd = L&7, b = xcd + 8*(wq/25), strip = wq%25, n0 = strip*8.
// S: 64 rows x 224 u16 = 28,672 B + bmS 3,136 B -> 5 blocks/CU.
// P1: scores via MFMA, th1 mix + bias fused in registers (fp32), store once.
__global__ __launch_bounds__(256, 5) void k_attn2(
    const u16* __restrict__ qt, const u16* __restrict__ kb16,
    const u16* __restrict__ vtT, const u16* __restrict__ vlt,
    const float* __restrict__ th1w, const float* __restrict__ th2w,
    const float* __restrict__ th2b, const float* __restrict__ biasmix,
    u16* __restrict__ ot)
{
    __shared__ u16 S[64 * SROW];
    __shared__ u16 bmS[8 * NSP];
    const int tid = threadIdx.x;
    const int L  = blockIdx.x;
    const int wq = L >> 3;
    const int b  = (L & 7) + ((wq / NSTRIP) << 3);
    const int n0 = (wq % NSTRIP) * 8;
    const int wid = tid >> 6, lane = tid & 63;
    const int l15 = lane & 15, lq8 = (lane >> 4) * 8;
    const int quad = lane >> 4, col = lane & 15;

    for (int i = tid; i < 8 * NSP; i += 256) bmS[i] = f2b(biasmix[i]);
    __syncthreads();

    // ---- phase 1: scores (MFMA) + th1 mix + bias, fused in registers ----
    {
        const long qrow = ((long)(b * NSP) + n0 + l15) * NQK;
        bf16x8 af[8];
        #pragma unroll
        for (int g = 0; g < 8; ++g)
            af[g] = *(const bf16x8*)&qt[qrow + g * 32 + lq8];
        #pragma unroll
        for (int jj = 0; jj < 4; ++jj) {
            const int j = wid + jj * 4;
            if (j >= 14) break;
            const long krow = ((long)(b * NSP) + j * 16 + l15) * NQK;
            f32x4 t[8];
            #pragma unroll
            for (int g = 0; g < 8; ++g) {
                bf16x8 bv = *(const bf16x8*)&kb16[krow + g * 32 + lq8];
                t[g] = __builtin_amdgcn_mfma_f32_16x16x32_bf16(
                    af[g], bv, (f32x4){0.f, 0.f, 0.f, 0.f}, 0, 0, 0);
            }
            if (quad < 2) {
                const int m = j * 16 + col;
                const int ym = m / RES, xm = m - ym * RES;
                int offr[4];
                #pragma unroll
                for (int r = 0; r < 4; ++r) {
                    int gn = n0 + quad * 4 + r;
                    int yn = gn / RES, xn = gn - yn * RES;
                    int off = abs(yn - ym) * RES + abs(xn - xm);
                    offr[r] = (off > 195) ? 195 : off;   // garbage rows only
                }
                #pragma unroll
                for (int h = 0; h < 8; ++h) {
                    float o[4];
                    #pragma unroll
                    for (int r = 0; r < 4; ++r) o[r] = b2f(bmS[h * NSP + offr[r]]);
                    #pragma unroll
                    for (int g = 0; g < 8; ++g) {
                        const float w = th1w[h * 8 + g] * SCALE;  // SGPR
                        #pragma unroll
                        for (int r = 0; r < 4; ++r) o[r] += w * t[g][r];
                    }
                    #pragma unroll
                    for (int r = 0; r < 4; ++r)
                        S[(h * 8 + quad * 4 + r) * SROW + m] = f2b(o[r]);
                }
            }
        }
    }
    __syncthreads();

    // ---- phase 3: softmax, 4 rows per wave concurrently (16-lane groups) ----
    {
        const int c = lane & 15, rg = lane >> 4;
        #pragma unroll
        for (int it = 0; it < 4; ++it) {
            u16* row = &S[(wid * 16 + it * 4 + rg) * SROW];
            float v[13];
            #pragma unroll
            for (int k = 0; k < 12; ++k) v[k] = b2f(row[c + 16 * k]);
            v[12] = (c < 4) ? b2f(row[192 + c]) : -1e30f;
            float mx = v[0];
            #pragma unroll
            for (int k = 1; k < 13; ++k) mx = fmaxf(mx, v[k]);
            #pragma unroll
            for (int o = 1; o < 16; o <<= 1) mx = fmaxf(mx, __shfl_xor(mx, o));
            float sum = 0.f;
            #pragma unroll
            for (int k = 0; k < 13; ++k) { v[k] = __expf(v[k] - mx); sum += v[k]; }
            if (c >= 4) sum -= v[12];   // garbage lane contribution
            #pragma unroll
            for (int o = 1; o < 16; o <<= 1) sum += __shfl_xor(sum, o);
            float inv = 1.0f / sum;
            #pragma unroll
            for (int k = 0; k < 12; ++k) row[c + 16 * k] = f2b(v[k] * inv);
            if (c < 4) row[192 + c] = f2b(v[12] * inv);
        }
    }
    __syncthreads();

    // ---- phase 4: th2 mix (+bias), zero pad m in [196,224), paired u32 ----
    {
        for (int p = tid; p < 8 * 112; p += 256) {
            const int nl = p / 112, kp = p - nl * 112;
            const int m0 = kp * 2;
            if (m0 >= NSP) {
                #pragma unroll
                for (int h = 0; h < 8; ++h)
                    *(u32*)&S[(h * 8 + nl) * SROW + m0] = 0u;
                continue;
            }
            float s0[8], s1[8];
            #pragma unroll
            for (int g = 0; g < 8; ++g) {
                u32 v = *(const u32*)&S[(g * 8 + nl) * SROW + m0];
                s0[g] = b2f((u16)(v & 0xffff));
                s1[g] = b2f((u16)(v >> 16));
            }
            #pragma unroll
            for (int h = 0; h < 8; ++h) {
                float o0 = th2b[h], o1 = th2b[h];
                #pragma unroll
                for (int g = 0; g < 8; ++g) {
                    const float w = th2w[h * 8 + g];   // SGPR
                    o0 += w * s0[g];
                    o1 += w * s1[g];
                }
                *(u32*)&S[(h * 8 + nl) * SROW + m0] =
                    (u32)f2b(o0) | ((u32)f2b(o1) << 16);
            }
        }
    }
    __syncthreads();

    // ---- phase 5: O = P @ V + vlocal, ReLU (M rows 8..15 are dupes) ----
    #pragma unroll
    for (int hh = 0; hh < 2; ++hh) {
        const int h = wid * 2 + hh;
        const long vrow = (long)(b * NHD + h) * DVV;
        f32x4 acc[8];
        #pragma unroll
        for (int df = 0; df < 8; ++df) acc[df] = (f32x4){0.f, 0.f, 0.f, 0.f};
        for (int kc = 0; kc < 7; ++kc) {
            bf16x8 a0 = *(const bf16x8*)&S[(h * 8 + (l15 & 7)) * SROW + kc * 32 + lq8];
            #pragma unroll
            for (int df = 0; df < 8; ++df) {
                bf16x8 bv = *(const bf16x8*)&vtT[(vrow + df * 16 + l15) * 224 + kc * 32 + lq8];
                acc[df] = __builtin_amdgcn_mfma_f32_16x16x32_bf16(a0, bv, acc[df], 0, 0, 0);
            }
        }
        if (quad < 2) {
            const long lbase = (long)(b * NHD + h) * NSP;
            #pragma unroll
            for (int df = 0; df < 8; ++df) {
                #pragma unroll
                for (int r = 0; r < 4; ++r) {
                    int n = n0 + quad * 4 + r;
                    int d = df * 16 + col;
                    if (n < NSP) {
                        float v = acc[df][r] + b2f(vlt[(lbase + n) * DVV + d]);
                        v = fmaxf(v, 0.f);
                        ot[((long)(b * NSP + n)) * 1024 + h * DVV + d] = f2b(v);
                    }
                }
            }
        }
    }
}

// ---------------- K5: output projection (MFMA), 128oc x 64m tiles ----------
__global__ __launch_bounds__(256) void k_proj(
    const u16* __restrict__ pwb, const u16* __restrict__ ot,
    const float* __restrict__ projb, float* __restrict__ outp)
{
    __shared__ u16 A_lds[4096];   // 128 rows x 32
    __shared__ u16 B_lds[2048];   // 64 rows x 32
    const int tid = threadIdx.x, wid = tid >> 6, lane = tid & 63;
    const int lrow = lane >> 2, lcb = (lane & 3) << 4;
    const int m0 = blockIdx.x * 64, oc0 = blockIdx.y * 128;
    const int wm = (wid & 1) * 64, wn = (wid >> 1) * 32;
    const int l15 = lane & 15, lq8 = (lane >> 4) * 8;

    const char* gp[3];
    u16* lp[3];
    #pragma unroll
    for (int s = 0; s < 3; ++s) {
        int seg = wid * 3 + s;
        if (seg < 8) {
            gp[s] = (const char*)pwb + (long)(oc0 + seg * 16 + lrow) * 2048 + lcb;
            lp[s] = A_lds + seg * 16 * 32;
        } else {
            gp[s] = (const char*)ot + (long)(m0 + (seg - 8) * 16 + lrow) * 2048 + lcb;
            lp[s] = B_lds + (seg - 8) * 16 * 32;
        }
    }

    f32x4 acc[4][2];
    #pragma unroll
    for (int i = 0; i < 4; ++i)
        #pragma unroll
        for (int j = 0; j < 2; ++j) acc[i][j] = (f32x4){0.f, 0.f, 0.f, 0.f};

    for (int kk = 0; kk < 32; ++kk) {
        gld16(gp[0], lp[0]); gld16(gp[1], lp[1]); gld16(gp[2], lp[2]);
        gp[0] += 64; gp[1] += 64; gp[2] += 64;
        __syncthreads();
        bf16x8 af[4], bfr[2];
        #pragma unroll
        for (int i = 0; i < 4; ++i)
            af[i] = *(const bf16x8*)&A_lds[(wm + i * 16 + l15) * 32 + lq8];
        #pragma unroll
        for (int j = 0; j < 2; ++j)
            bfr[j] = *(const bf16x8*)&B_lds[(wn + j * 16 + l15) * 32 + lq8];
        #pragma unroll
        for (int i = 0; i < 4; ++i)
            #pragma unroll
            for (int j = 0; j < 2; ++j)
                acc[i][j] = __builtin_amdgcn_mfma_f32_16x16x32_bf16(
                    af[i], bfr[j], acc[i][j], 0, 0, 0);
        __syncthreads();
    }

    const int col = lane & 15, quad = lane >> 4;
    #pragma unroll
    for (int i = 0; i < 4; ++i) {
        #pragma unroll
        for (int j = 0; j < 2; ++j) {
            #pragma unroll
            for (int r = 0; r < 4; ++r) {
                int oc = oc0 + wm + i * 16 + quad * 4 + r;
                int mg = m0 + wn + j * 16 + col;
                int b = mg / NSP, n = mg - b * NSP;
                outp[((long)b * DIM + oc) * NSP + n] = acc[i][j][r] + projb[oc];
            }
        }
    }
}

extern "C" void kernel_launch(void* const* d_in, const int* in_sizes, int n_in,
                              void* d_out, int out_size, void* d_ws, size_t ws_size,
                              hipStream_t stream) {
    const float* x        = (const float*)d_in[0];
    const float* qw       = (const float*)d_in[1];
    const float* qb       = (const float*)d_in[2];
    const float* kw       = (const float*)d_in[3];
    const float* kb       = (const float*)d_in[4];
    const float* vw       = (const float*)d_in[5];
    const float* vb       = (const float*)d_in[6];
    const float* vlw      = (const float*)d_in[7];
    const float* vlb      = (const float*)d_in[8];
    const float* th1w     = (const float*)d_in[9];
    const float* th1b     = (const float*)d_in[10];
    const float* th2w     = (const float*)d_in[11];
    const float* th2b     = (const float*)d_in[12];
    const float* projw    = (const float*)d_in[13];
    const float* projb    = (const float*)d_in[14];
    const float* bias_seg = (const float*)d_in[15];
    float* outp = (float*)d_out;

    // workspace layout (bytes, 16B aligned)
    char* w = (char*)d_ws;
    u16* xb      = (u16*)(w);                 //  9,633,792
    u16* wqkv    = (u16*)(w + 9633792);       //  1,179,648
    u16* pwb     = (u16*)(w + 10813440);      //    786,432
    u16* wpack   = (u16*)(w + 11599872);      //     18,432
    float* bmix  = (float*)(w + 11618304);    //      6,400
    u16* qt      = (u16*)(w + 11624704);      //  6,455,296 (12608 rows x 256)
    u16* kb16    = (u16*)(w + 18080000);      //  6,455,296
    u16* vt      = (u16*)(w + 24535296);      // 25,690,112
    u16* vtT     = (u16*)(w + 50225408);      // 29,360,128
    u16* ot      = (u16*)(w + 79585536);      // 25,690,112
    u16* vlt     = (u16*)(w + 105275648);     // 25,690,112
    // total 130,965,760 B

    k_prep_w<<<dim3(3883), 256, 0, stream>>>(qw, kw, vw, projw, th1w, th1b,
                                             bias_seg, vlw, wqkv, pwb, bmix, wpack);
    k_prep_x<<<dim3(7, 12, 64), 256, 0, stream>>>(x, xb);
    k_qkv<<<dim3(98, 12), 256, 0, stream>>>(xb, wqkv, qb, kb, vb, qt, kb16, vt);
    k_vtT<<<dim3(7, 4, 512), 256, 0, stream>>>(vt, vtT);
    k_dwconv<<<dim3(13, 512), 256, 0, stream>>>(vt, wpack, vlb, vlt);
    k_attn2<<<dim3(NSTRIP * 64), 256, 0, stream>>>(qt, kb16, vtT, vlt, th1w, th2w,
                                                   th2b, bmix, ot);
    k_proj<<<dim3(196, 3), 256, 0, stream>>>(pwb, ot, projb, outp);
}

// Round 10
// 306.044 us; speedup vs baseline: 1.1493x; 1.1493x over previous
//
#include <hip/hip_runtime.h>
#include <hip/hip_bf16.h>

// Attention4D MI355X round 10:
//  k_attn2: 512-thread blocks x 16-row strips. Halves per-batch V L2 traffic
//  vs 8-row strips (13 blocks/b not 25) while keeping 16 waves/CU (2 blocks
//  x 8 waves, 60.5KB LDS). 16x16 MFMA M-dim now fully used in phases 1&5
//  (no quad<2 idle lanes). Keeps XCD-affinity swizzle.
// B=64, DIM=384, N=196 (14x14), NH=8, KD=32, DV=128.

#define RES   14
#define NSP   196
#define NHD   8
#define KDIM  32
#define DVV   128
#define DIM   384
#define NQK   256
#define SCALE 0.17677669529663687f
#define SROW  224    // LDS score row stride (u16); 448B ≡ bank16: 2-way, free
#define NSTRIP 13    // 13 x 16 = 208 >= 196

typedef __attribute__((ext_vector_type(8))) short bf16x8;
typedef __attribute__((ext_vector_type(4))) float f32x4;
typedef unsigned short u16;
typedef unsigned int u32;

__device__ __forceinline__ u16 f2b(float f) {
    union { __hip_bfloat16 b; u16 u; } c; c.b = __float2bfloat16(f); return c.u;
}
__device__ __forceinline__ float b2f(u16 u) {
    union { __hip_bfloat16 b; u16 u; } c; c.u = u; return __bfloat162float(c.b);
}

// async global->LDS, 16B per lane; LDS dest = wave-uniform base + lane*16
__device__ __forceinline__ void gld16(const void* g, void* l) {
    __builtin_amdgcn_global_load_lds(
        (__attribute__((address_space(1))) void*)(unsigned long long)(const char*)g,
        (__attribute__((address_space(3))) void*)l, 16, 0, 0);
}

// ---- shared 128x128 bf16 MFMA GEMM core (m97 structure) ----
__device__ __forceinline__ void gemm128(const char* Aseg, long rbA,
                                        const char* Bseg, long rbB, int kIters,
                                        u16* A_lds, u16* B_lds, f32x4 acc[4][4])
{
    const int tid  = threadIdx.x;
    const int wid  = tid >> 6;
    const int lane = tid & 63;
    const int lrow = lane >> 2;
    const int lcb  = (lane & 3) << 4;
    const int r0   = wid * 32;
    const int wm   = (wid & 1) * 64, wn = (wid >> 1) * 64;
    const int l15  = lane & 15, lq8 = (lane >> 4) * 8;

    #pragma unroll
    for (int i = 0; i < 4; ++i)
        #pragma unroll
        for (int j = 0; j < 4; ++j) acc[i][j] = (f32x4){0.f, 0.f, 0.f, 0.f};

    const char* ap0 = Aseg + (long)(r0 + lrow) * rbA + lcb;
    const char* ap1 = ap0 + 16 * rbA;
    const char* bp0 = Bseg + (long)(r0 + lrow) * rbB + lcb;
    const char* bp1 = bp0 + 16 * rbB;
    u16* la0 = A_lds + r0 * 32;
    u16* la1 = A_lds + (r0 + 16) * 32;
    u16* lb0 = B_lds + r0 * 32;
    u16* lb1 = B_lds + (r0 + 16) * 32;

    for (int kk = 0; kk < kIters; ++kk) {
        gld16(ap0, la0); gld16(ap1, la1);
        gld16(bp0, lb0); gld16(bp1, lb1);
        ap0 += 64; ap1 += 64; bp0 += 64; bp1 += 64;
        __syncthreads();
        bf16x8 af[4], bfr[4];
        #pragma unroll
        for (int i = 0; i < 4; ++i)
            af[i] = *(const bf16x8*)&A_lds[(wm + i * 16 + l15) * 32 + lq8];
        #pragma unroll
        for (int j = 0; j < 4; ++j)
            bfr[j] = *(const bf16x8*)&B_lds[(wn + j * 16 + l15) * 32 + lq8];
        #pragma unroll
        for (int i = 0; i < 4; ++i)
            #pragma unroll
            for (int j = 0; j < 4; ++j)
                acc[i][j] = __builtin_amdgcn_mfma_f32_16x16x32_bf16(
                    af[i], bfr[j], acc[i][j], 0, 0, 0);
        __syncthreads();
    }
}

// ---------------- prep: weights fp32 -> bf16, biasmix, wpack ----------------
__global__ __launch_bounds__(256) void k_prep_w(
    const float* __restrict__ qw, const float* __restrict__ kw,
    const float* __restrict__ vw, const float* __restrict__ pw,
    const float* __restrict__ th1w, const float* __restrict__ th1b,
    const float* __restrict__ bias_seg, const float* __restrict__ vlw,
    u16* __restrict__ wqkv, u16* __restrict__ pwb, float* __restrict__ biasmix,
    u16* __restrict__ wpack)
{
    int i = blockIdx.x * 256 + threadIdx.x;
    if (i < 98304)       wqkv[i] = f2b(qw[i]);
    else if (i < 196608) wqkv[i] = f2b(kw[i - 98304]);
    else if (i < 589824) wqkv[i] = f2b(vw[i - 196608]);
    else if (i < 983040) pwb[i - 589824] = f2b(pw[i - 589824]);
    else if (i < 984608) {
        int i2 = i - 983040;
        int hh = i2 / NSP, off = i2 - hh * NSP;
        float a = th1b[hh];
        #pragma unroll
        for (int g = 0; g < 8; ++g) a += th1w[hh * 8 + g] * bias_seg[g * NSP + off];
        biasmix[i2] = a;
    } else if (i < 993824) {
        int i2 = i - 984608;          // wpack[g*72 + tap*8 + t] = vlw[(g*8+t)*9+tap]
        int g = i2 / 72, r = i2 - g * 72;
        int tap = r >> 3, t = r & 7;
        wpack[i2] = f2b(vlw[(g * 8 + t) * 9 + tap]);
    }
}

// ---------------- prep: x (b,c,n) fp32 -> xb (b*n, c) bf16 ----------------
__global__ __launch_bounds__(256) void k_prep_x(
    const float* __restrict__ x, u16* __restrict__ xb)
{
    __shared__ float t[32][33];
    const int b = blockIdx.z, c0 = blockIdx.y * 32, n0 = blockIdx.x * 32;
    const int tx = threadIdx.x & 31, ty = threadIdx.x >> 5;
    #pragma unroll
    for (int l = 0; l < 4; ++l) {
        int c = c0 + ty + 8 * l, n = n0 + tx;
        t[ty + 8 * l][tx] = (n < NSP) ? x[((long)b * DIM + c) * NSP + n] : 0.f;
    }
    __syncthreads();
    #pragma unroll
    for (int l = 0; l < 4; ++l) {
        int n = n0 + ty + 8 * l, c = c0 + tx;
        if (n < NSP) xb[((long)b * NSP + n) * DIM + c] = f2b(t[tx][ty + 8 * l]);
    }
}

// ---------------- K1: QKV projection (MFMA) ----------------
__global__ __launch_bounds__(256) void k_qkv(
    const u16* __restrict__ xb, const u16* __restrict__ wqkv,
    const float* __restrict__ qb, const float* __restrict__ kb,
    const float* __restrict__ vb,
    u16* __restrict__ qt, u16* __restrict__ kb16, u16* __restrict__ vt)
{
    __shared__ u16 A_lds[4096], B_lds[4096];
    const int m0 = blockIdx.x * 128, oc0 = blockIdx.y * 128;
    f32x4 acc[4][4];
    gemm128((const char*)xb + (long)m0 * 768, 768,
            (const char*)wqkv + (long)oc0 * 768, 768, 12, A_lds, B_lds, acc);

    const int tid = threadIdx.x, wid = tid >> 6, lane = tid & 63;
    const int wm = (wid & 1) * 64, wn = (wid >> 1) * 64;
    const int col = lane & 15, quad = lane >> 4;
    #pragma unroll
    for (int i = 0; i < 4; ++i) {
        #pragma unroll
        for (int j = 0; j < 4; ++j) {
            #pragma unroll
            for (int r = 0; r < 4; ++r) {
                int m  = m0 + wm + i * 16 + quad * 4 + r;
                int oc = oc0 + wn + j * 16 + col;
                int b = m / NSP, n = m - b * NSP;
                float v = acc[i][j][r];
                if (oc < 256) {
                    qt[(long)m * NQK + oc] = f2b(v + qb[oc]);
                } else if (oc < 512) {
                    int o = oc - 256;
                    kb16[(long)m * NQK + o] = f2b(v + kb[o]);
                } else {
                    int o = oc - 512, h = o >> 7, d = o & 127;
                    vt[(((long)b * NHD + h) * NSP + n) * DVV + d] = f2b(v + vb[o]);
                }
            }
        }
    }
}

// ---------------- prep: vt -> vtT (bh, d, m) rows padded to 224 ----------
__global__ __launch_bounds__(256) void k_vtT(
    const u16* __restrict__ vt, u16* __restrict__ vtT)
{
    __shared__ u16 t[32][33];
    const int bh = blockIdx.z, d0 = blockIdx.y * 32, n0 = blockIdx.x * 32;
    const int tx = threadIdx.x & 31, ty = threadIdx.x >> 5;
    #pragma unroll
    for (int l = 0; l < 4; ++l) {
        int n = n0 + ty + 8 * l, d = d0 + tx;
        t[ty + 8 * l][tx] = (n < NSP) ? vt[((long)bh * NSP + n) * DVV + d] : (u16)0;
    }
    __syncthreads();
    #pragma unroll
    for (int l = 0; l < 4; ++l) {
        int d = d0 + ty + 8 * l, m = n0 + tx;
        vtT[((long)bh * DVV + d) * 224 + m] = t[tx][ty + 8 * l];
    }
}

// ---------------- K2: depthwise 3x3 conv, vectorized over 8 d ----------------
__global__ __launch_bounds__(256) void k_dwconv(
    const u16* __restrict__ vt, const u16* __restrict__ wpack,
    const float* __restrict__ vlb, u16* __restrict__ vlt)
{
    const int tid = threadIdx.x;
    const int dg = tid & 15;                 // d0 = dg*8
    const int nl = tid >> 4;                 // 16 n per block
    const int bh = blockIdx.y;
    const int n  = blockIdx.x * 16 + nl;
    if (n >= NSP) return;
    const int d0 = dg * 8;
    const int h  = bh & 7;
    const int y = n / RES, xx = n - y * RES;
    const long plane = (long)bh * NSP * DVV;
    float acc[8];
    #pragma unroll
    for (int t = 0; t < 8; ++t) acc[t] = vlb[h * DVV + d0 + t];
    const u16* wb = wpack + (h * 16 + dg) * 72;
    #pragma unroll
    for (int dy = -1; dy <= 1; ++dy) {
        int yy = y + dy;
        if (yy < 0 || yy >= RES) continue;
        #pragma unroll
        for (int dx = -1; dx <= 1; ++dx) {
            int xn = xx + dx;
            if (xn < 0 || xn >= RES) continue;
            int tap = (dy + 1) * 3 + dx + 1;
            bf16x8 v  = *(const bf16x8*)&vt[plane + (yy * RES + xn) * DVV + d0];
            bf16x8 wv = *(const bf16x8*)&wb[tap * 8];
            #pragma unroll
            for (int t = 0; t < 8; ++t)
                acc[t] += b2f((u16)wv[t]) * b2f((u16)v[t]);
        }
    }
    bf16x8 r;
    #pragma unroll
    for (int t = 0; t < 8; ++t) r[t] = (short)f2b(acc[t]);
    *(bf16x8*)&vlt[plane + (long)n * DVV + d0] = r;
}

// ---------------- K3: fused attention middle, 512 thr x 16-row strips ------
// grid 832: xcd = L&7, b = xcd + 8*(wq/13), strip = wq%13, n0 = strip*16.
// S: 128 rows x 224 u16 = 57,344 B + bmS 3,136 B -> 2 blocks/CU (16 waves).
__global__ __launch_bounds__(512, 4) void k_attn2(
    const u16* __restrict__ qt, const u16* __restrict__ kb16,
    const u16* __restrict__ vtT, const u16* __restrict__ vlt,
    const float* __restrict__ th1w, const float* __restrict__ th2w,
    const float* __restrict__ th2b, const float* __restrict__ biasmix,
    u16* __restrict__ ot)
{
    __shared__ u16 S[128 * SROW];
    __shared__ u16 bmS[8 * NSP];
    const int tid = threadIdx.x;
    const int L  = blockIdx.x;
    const int wq = L >> 3;
    const int b  = (L & 7) + ((wq / NSTRIP) << 3);
    const int n0 = (wq % NSTRIP) * 16;
    const int wid = tid >> 6, lane = tid & 63;
    const int l15 = lane & 15, lq8 = (lane >> 4) * 8;
    const int quad = lane >> 4, col = lane & 15;

    for (int i = tid; i < 8 * NSP; i += 512) bmS[i] = f2b(biasmix[i]);
    __syncthreads();

    // ---- phase 1: scores (MFMA) + th1 mix + bias, fused in registers ----
    // 16 A-rows (full M), wave w handles j = w and j = w + 8 (j < 14).
    {
        const long qrow = ((long)(b * NSP) + n0 + l15) * NQK;
        bf16x8 af[8];
        #pragma unroll
        for (int g = 0; g < 8; ++g)
            af[g] = *(const bf16x8*)&qt[qrow + g * 32 + lq8];
        #pragma unroll
        for (int jj = 0; jj < 2; ++jj) {
            const int j = wid + jj * 8;
            if (j >= 14) break;
            const long krow = ((long)(b * NSP) + j * 16 + l15) * NQK;
            f32x4 t[8];
            #pragma unroll
            for (int g = 0; g < 8; ++g) {
                bf16x8 bv = *(const bf16x8*)&kb16[krow + g * 32 + lq8];
                t[g] = __builtin_amdgcn_mfma_f32_16x16x32_bf16(
                    af[g], bv, (f32x4){0.f, 0.f, 0.f, 0.f}, 0, 0, 0);
            }
            const int m = j * 16 + col;
            const int ym = m / RES, xm = m - ym * RES;
            int offr[4];
            #pragma unroll
            for (int r = 0; r < 4; ++r) {
                int gn = n0 + quad * 4 + r;
                int yn = gn / RES, xn = gn - yn * RES;
                int off = abs(yn - ym) * RES + abs(xn - xm);
                offr[r] = (off > 195) ? 195 : off;   // garbage rows/cols only
            }
            #pragma unroll
            for (int h = 0; h < 8; ++h) {
                float o[4];
                #pragma unroll
                for (int r = 0; r < 4; ++r) o[r] = b2f(bmS[h * NSP + offr[r]]);
                #pragma unroll
                for (int g = 0; g < 8; ++g) {
                    const float w = th1w[h * 8 + g] * SCALE;  // SGPR
                    #pragma unroll
                    for (int r = 0; r < 4; ++r) o[r] += w * t[g][r];
                }
                #pragma unroll
                for (int r = 0; r < 4; ++r)
                    S[(h * 16 + quad * 4 + r) * SROW + m] = f2b(o[r]);
            }
        }
    }
    __syncthreads();

    // ---- phase 3: softmax, 4 rows per wave concurrently (16-lane groups) ----
    {
        const int c = lane & 15, rg = lane >> 4;
        #pragma unroll
        for (int it = 0; it < 4; ++it) {
            u16* row = &S[(wid * 16 + it * 4 + rg) * SROW];
            float v[13];
            #pragma unroll
            for (int k = 0; k < 12; ++k) v[k] = b2f(row[c + 16 * k]);
            v[12] = (c < 4) ? b2f(row[192 + c]) : -1e30f;
            float mx = v[0];
            #pragma unroll
            for (int k = 1; k < 13; ++k) mx = fmaxf(mx, v[k]);
            #pragma unroll
            for (int o = 1; o < 16; o <<= 1) mx = fmaxf(mx, __shfl_xor(mx, o));
            float sum = 0.f;
            #pragma unroll
            for (int k = 0; k < 13; ++k) { v[k] = __expf(v[k] - mx); sum += v[k]; }
            if (c >= 4) sum -= v[12];   // garbage lane contribution
            #pragma unroll
            for (int o = 1; o < 16; o <<= 1) sum += __shfl_xor(sum, o);
            float inv = 1.0f / sum;
            #pragma unroll
            for (int k = 0; k < 12; ++k) row[c + 16 * k] = f2b(v[k] * inv);
            if (c < 4) row[192 + c] = f2b(v[12] * inv);
        }
    }
    __syncthreads();

    // ---- phase 4: th2 mix (+bias), zero pad m in [196,224), paired u32 ----
    {
        for (int p = tid; p < 16 * 112; p += 512) {
            const int nl = p / 112, kp = p - nl * 112;
            const int m0 = kp * 2;
            if (m0 >= NSP) {
                #pragma unroll
                for (int h = 0; h < 8; ++h)
                    *(u32*)&S[(h * 16 + nl) * SROW + m0] = 0u;
                continue;
            }
            float s0[8], s1[8];
            #pragma unroll
            for (int g = 0; g < 8; ++g) {
                u32 v = *(const u32*)&S[(g * 16 + nl) * SROW + m0];
                s0[g] = b2f((u16)(v & 0xffff));
                s1[g] = b2f((u16)(v >> 16));
            }
            #pragma unroll
            for (int h = 0; h < 8; ++h) {
                float o0 = th2b[h], o1 = th2b[h];
                #pragma unroll
                for (int g = 0; g < 8; ++g) {
                    const float w = th2w[h * 8 + g];   // SGPR
                    o0 += w * s0[g];
                    o1 += w * s1[g];
                }
                *(u32*)&S[(h * 16 + nl) * SROW + m0] =
                    (u32)f2b(o0) | ((u32)f2b(o1) << 16);
            }
        }
    }
    __syncthreads();

    // ---- phase 5: O = P @ V + vlocal, ReLU (one head per wave, full M) ----
    {
        const int h = wid;
        const long vrow = (long)(b * NHD + h) * DVV;
        f32x4 acc[8];
        #pragma unroll
        for (int df = 0; df < 8; ++df) acc[df] = (f32x4){0.f, 0.f, 0.f, 0.f};
        for (int kc = 0; kc < 7; ++kc) {
            bf16x8 a0 = *(const bf16x8*)&S[(h * 16 + l15) * SROW + kc * 32 + lq8];
            #pragma unroll
            for (int df = 0; df < 8; ++df) {
                bf16x8 bv = *(const bf16x8*)&vtT[(vrow + df * 16 + l15) * 224 + kc * 32 + lq8];
                acc[df] = __builtin_amdgcn_mfma_f32_16x16x32_bf16(a0, bv, acc[df], 0, 0, 0);
            }
        }
        const long lbase = (long)(b * NHD + h) * NSP;
        #pragma unroll
        for (int df = 0; df < 8; ++df) {
            #pragma unroll
            for (int r = 0; r < 4; ++r) {
                int n = n0 + quad * 4 + r;
                int d = df * 16 + col;
                if (n < NSP) {
                    float v = acc[df][r] + b2f(vlt[(lbase + n) * DVV + d]);
                    v = fmaxf(v, 0.f);
                    ot[((long)(b * NSP + n)) * 1024 + h * DVV + d] = f2b(v);
                }
            }
        }
    }
}

// ---------------- K5: output projection (MFMA), 128oc x 64m tiles ----------
__global__ __launch_bounds__(256) void k_proj(
    const u16* __restrict__ pwb, const u16* __restrict__ ot,
    const float* __restrict__ projb, float* __restrict__ outp)
{
    __shared__ u16 A_lds[4096];   // 128 rows x 32
    __shared__ u16 B_lds[2048];   // 64 rows x 32
    const int tid = threadIdx.x, wid = tid >> 6, lane = tid & 63;
    const int lrow = lane >> 2, lcb = (lane & 3) << 4;
    const int m0 = blockIdx.x * 64, oc0 = blockIdx.y * 128;
    const int wm = (wid & 1) * 64, wn = (wid >> 1) * 32;
    const int l15 = lane & 15, lq8 = (lane >> 4) * 8;

    const char* gp[3];
    u16* lp[3];
    #pragma unroll
    for (int s = 0; s < 3; ++s) {
        int seg = wid * 3 + s;
        if (seg < 8) {
            gp[s] = (const char*)pwb + (long)(oc0 + seg * 16 + lrow) * 2048 + lcb;
            lp[s] = A_lds + seg * 16 * 32;
        } else {
            gp[s] = (const char*)ot + (long)(m0 + (seg - 8) * 16 + lrow) * 2048 + lcb;
            lp[s] = B_lds + (seg - 8) * 16 * 32;
        }
    }

    f32x4 acc[4][2];
    #pragma unroll
    for (int i = 0; i < 4; ++i)
        #pragma unroll
        for (int j = 0; j < 2; ++j) acc[i][j] = (f32x4){0.f, 0.f, 0.f, 0.f};

    for (int kk = 0; kk < 32; ++kk) {
        gld16(gp[0], lp[0]); gld16(gp[1], lp[1]); gld16(gp[2], lp[2]);
        gp[0] += 64; gp[1] += 64; gp[2] += 64;
        __syncthreads();
        bf16x8 af[4], bfr[2];
        #pragma unroll
        for (int i = 0; i < 4; ++i)
            af[i] = *(const bf16x8*)&A_lds[(wm + i * 16 + l15) * 32 + lq8];
        #pragma unroll
        for (int j = 0; j < 2; ++j)
            bfr[j] = *(const bf16x8*)&B_lds[(wn + j * 16 + l15) * 32 + lq8];
        #pragma unroll
        for (int i = 0; i < 4; ++i)
            #pragma unroll
            for (int j = 0; j < 2; ++j)
                acc[i][j] = __builtin_amdgcn_mfma_f32_16x16x32_bf16(
                    af[i], bfr[j], acc[i][j], 0, 0, 0);
        __syncthreads();
    }

    const int col = lane & 15, quad = lane >> 4;
    #pragma unroll
    for (int i = 0; i < 4; ++i) {
        #pragma unroll
        for (int j = 0; j < 2; ++j) {
            #pragma unroll
            for (int r = 0; r < 4; ++r) {
                int oc = oc0 + wm + i * 16 + quad * 4 + r;
                int mg = m0 + wn + j * 16 + col;
                int b = mg / NSP, n = mg - b * NSP;
                outp[((long)b * DIM + oc) * NSP + n] = acc[i][j][r] + projb[oc];
            }
        }
    }
}

extern "C" void kernel_launch(void* const* d_in, const int* in_sizes, int n_in,
                              void* d_out, int out_size, void* d_ws, size_t ws_size,
                              hipStream_t stream) {
    const float* x        = (const float*)d_in[0];
    const float* qw       = (const float*)d_in[1];
    const float* qb       = (const float*)d_in[2];
    const float* kw       = (const float*)d_in[3];
    const float* kb       = (const float*)d_in[4];
    const float* vw       = (const float*)d_in[5];
    const float* vb       = (const float*)d_in[6];
    const float* vlw      = (const float*)d_in[7];
    const float* vlb      = (const float*)d_in[8];
    const float* th1w     = (const float*)d_in[9];
    const float* th1b     = (const float*)d_in[10];
    const float* th2w     = (const float*)d_in[11];
    const float* th2b     = (const float*)d_in[12];
    const float* projw    = (const float*)d_in[13];
    const float* projb    = (const float*)d_in[14];
    const float* bias_seg = (const float*)d_in[15];
    float* outp = (float*)d_out;

    // workspace layout (bytes, 16B aligned)
    char* w = (char*)d_ws;
    u16* xb      = (u16*)(w);                 //  9,633,792
    u16* wqkv    = (u16*)(w + 9633792);       //  1,179,648
    u16* pwb     = (u16*)(w + 10813440);      //    786,432
    u16* wpack   = (u16*)(w + 11599872);      //     18,432
    float* bmix  = (float*)(w + 11618304);    //      6,400
    u16* qt      = (u16*)(w + 11624704);      //  6,455,296 (12608 rows x 256)
    u16* kb16    = (u16*)(w + 18080000);      //  6,455,296
    u16* vt      = (u16*)(w + 24535296);      // 25,690,112
    u16* vtT     = (u16*)(w + 50225408);      // 29,360,128
    u16* ot      = (u16*)(w + 79585536);      // 25,690,112
    u16* vlt     = (u16*)(w + 105275648);     // 25,690,112
    // total 130,965,760 B

    k_prep_w<<<dim3(3883), 256, 0, stream>>>(qw, kw, vw, projw, th1w, th1b,
                                             bias_seg, vlw, wqkv, pwb, bmix, wpack);
    k_prep_x<<<dim3(7, 12, 64), 256, 0, stream>>>(x, xb);
    k_qkv<<<dim3(98, 12), 256, 0, stream>>>(xb, wqkv, qb, kb, vb, qt, kb16, vt);
    k_vtT<<<dim3(7, 4, 512), 256, 0, stream>>>(vt, vtT);
    k_dwconv<<<dim3(13, 512), 256, 0, stream>>>(vt, wpack, vlb, vlt);
    k_attn2<<<dim3(NSTRIP * 64), 512, 0, stream>>>(qt, kb16, vtT, vlt, th1w, th2w,
                                                   th2b, bmix, ot);
    k_proj<<<dim3(196, 3), 256, 0, stream>>>(pwb, ot, projb, outp);
}

// Round 11
// 299.411 us; speedup vs baseline: 1.1748x; 1.0222x over previous
//
#include <hip/hip_runtime.h>
#include <hip/hip_bf16.h>

// Attention4D MI355X round 11:
//  - k_qkv / k_proj: BK=64 double-staged k-loop (two BK=32 sub-tiles per
//    barrier pair) -> half the __syncthreads/vmcnt drains of the m97 shape.
//  - k_prep_w + k_prep_x merged into one launch.
//  - k_attn2 (R10 512-thr/16-row version), k_vtT, k_dwconv unchanged.
// B=64, DIM=384, N=196 (14x14), NH=8, KD=32, DV=128.

#define RES   14
#define NSP   196
#define NHD   8
#define KDIM  32
#define DVV   128
#define DIM   384
#define NQK   256
#define SCALE 0.17677669529663687f
#define SROW  224    // LDS score row stride (u16); 448B ≡ bank16: 2-way, free
#define NSTRIP 13    // 13 x 16 = 208 >= 196

typedef __attribute__((ext_vector_type(8))) short bf16x8;
typedef __attribute__((ext_vector_type(4))) float f32x4;
typedef unsigned short u16;
typedef unsigned int u32;

__device__ __forceinline__ u16 f2b(float f) {
    union { __hip_bfloat16 b; u16 u; } c; c.b = __float2bfloat16(f); return c.u;
}
__device__ __forceinline__ float b2f(u16 u) {
    union { __hip_bfloat16 b; u16 u; } c; c.u = u; return __bfloat162float(c.b);
}

// async global->LDS, 16B per lane; LDS dest = wave-uniform base + lane*16
__device__ __forceinline__ void gld16(const void* g, void* l) {
    __builtin_amdgcn_global_load_lds(
        (__attribute__((address_space(1))) void*)(unsigned long long)(const char*)g,
        (__attribute__((address_space(3))) void*)l, 16, 0, 0);
}

// ---- 128x128 bf16 MFMA GEMM core, BK=64 (two BK=32 sub-tiles / barrier) ----
// A_lds, B_lds: 8192 u16 each (2 sub-tiles of 128 rows x 32 u16).
__device__ __forceinline__ void gemm128_bk64(const char* Aseg, long rbA,
                                             const char* Bseg, long rbB, int kIters,
                                             u16* A_lds, u16* B_lds, f32x4 acc[4][4])
{
    const int tid  = threadIdx.x;
    const int wid  = tid >> 6;
    const int lane = tid & 63;
    const int lrow = lane >> 2;
    const int lcb  = (lane & 3) << 4;
    const int r0   = wid * 32;
    const int wm   = (wid & 1) * 64, wn = (wid >> 1) * 64;
    const int l15  = lane & 15, lq8 = (lane >> 4) * 8;

    #pragma unroll
    for (int i = 0; i < 4; ++i)
        #pragma unroll
        for (int j = 0; j < 4; ++j) acc[i][j] = (f32x4){0.f, 0.f, 0.f, 0.f};

    const char* ap0 = Aseg + (long)(r0 + lrow) * rbA + lcb;
    const char* ap1 = ap0 + 16 * rbA;
    const char* bp0 = Bseg + (long)(r0 + lrow) * rbB + lcb;
    const char* bp1 = bp0 + 16 * rbB;
    u16* la0 = A_lds + r0 * 32;
    u16* la1 = la0 + 512;
    u16* lb0 = B_lds + r0 * 32;
    u16* lb1 = lb0 + 512;

    for (int kk = 0; kk < kIters; ++kk) {
        gld16(ap0, la0);        gld16(ap1, la1);
        gld16(bp0, lb0);        gld16(bp1, lb1);
        gld16(ap0 + 64, la0 + 4096); gld16(ap1 + 64, la1 + 4096);
        gld16(bp0 + 64, lb0 + 4096); gld16(bp1 + 64, lb1 + 4096);
        ap0 += 128; ap1 += 128; bp0 += 128; bp1 += 128;
        __syncthreads();
        #pragma unroll
        for (int s = 0; s < 2; ++s) {
            bf16x8 af[4], bfr[4];
            #pragma unroll
            for (int i = 0; i < 4; ++i)
                af[i] = *(const bf16x8*)&A_lds[s * 4096 + (wm + i * 16 + l15) * 32 + lq8];
            #pragma unroll
            for (int j = 0; j < 4; ++j)
                bfr[j] = *(const bf16x8*)&B_lds[s * 4096 + (wn + j * 16 + l15) * 32 + lq8];
            #pragma unroll
            for (int i = 0; i < 4; ++i)
                #pragma unroll
                for (int j = 0; j < 4; ++j)
                    acc[i][j] = __builtin_amdgcn_mfma_f32_16x16x32_bf16(
                        af[i], bfr[j], acc[i][j], 0, 0, 0);
        }
        __syncthreads();
    }
}

// ---------------- prep (merged): weights + biasmix + wpack + x transpose ----
// blocks [0,3883): elementwise weight conversions; [3883,9259): x transpose.
__global__ __launch_bounds__(256) void k_prep(
    const float* __restrict__ qw, const float* __restrict__ kw,
    const float* __restrict__ vw, const float* __restrict__ pw,
    const float* __restrict__ th1w, const float* __restrict__ th1b,
    const float* __restrict__ bias_seg, const float* __restrict__ vlw,
    const float* __restrict__ x,
    u16* __restrict__ wqkv, u16* __restrict__ pwb, float* __restrict__ biasmix,
    u16* __restrict__ wpack, u16* __restrict__ xb)
{
    __shared__ float t[32][33];
    const int bid = blockIdx.x;
    if (bid < 3883) {
        int i = bid * 256 + threadIdx.x;
        if (i < 98304)       wqkv[i] = f2b(qw[i]);
        else if (i < 196608) wqkv[i] = f2b(kw[i - 98304]);
        else if (i < 589824) wqkv[i] = f2b(vw[i - 196608]);
        else if (i < 983040) pwb[i - 589824] = f2b(pw[i - 589824]);
        else if (i < 984608) {
            int i2 = i - 983040;
            int hh = i2 / NSP, off = i2 - hh * NSP;
            float a = th1b[hh];
            #pragma unroll
            for (int g = 0; g < 8; ++g) a += th1w[hh * 8 + g] * bias_seg[g * NSP + off];
            biasmix[i2] = a;
        } else if (i < 993824) {
            int i2 = i - 984608;      // wpack[g*72 + tap*8 + t] = vlw[(g*8+t)*9+tap]
            int g = i2 / 72, r = i2 - g * 72;
            int tap = r >> 3, tt = r & 7;
            wpack[i2] = f2b(vlw[(g * 8 + tt) * 9 + tap]);
        }
    } else {
        const int L = bid - 3883;            // 5376 blocks
        const int b = L / 84, r = L - b * 84;
        const int c0 = (r / 7) * 32, n0 = (r % 7) * 32;
        const int tx = threadIdx.x & 31, ty = threadIdx.x >> 5;
        #pragma unroll
        for (int l = 0; l < 4; ++l) {
            int c = c0 + ty + 8 * l, n = n0 + tx;
            t[ty + 8 * l][tx] = (n < NSP) ? x[((long)b * DIM + c) * NSP + n] : 0.f;
        }
        __syncthreads();
        #pragma unroll
        for (int l = 0; l < 4; ++l) {
            int n = n0 + ty + 8 * l, c = c0 + tx;
            if (n < NSP) xb[((long)b * NSP + n) * DIM + c] = f2b(t[tx][ty + 8 * l]);
        }
    }
}

// ---------------- K1: QKV projection (MFMA, BK=64) ----------------
__global__ __launch_bounds__(256) void k_qkv(
    const u16* __restrict__ xb, const u16* __restrict__ wqkv,
    const float* __restrict__ qb, const float* __restrict__ kb,
    const float* __restrict__ vb,
    u16* __restrict__ qt, u16* __restrict__ kb16, u16* __restrict__ vt)
{
    __shared__ u16 A_lds[8192], B_lds[8192];
    const int m0 = blockIdx.x * 128, oc0 = blockIdx.y * 128;
    f32x4 acc[4][4];
    gemm128_bk64((const char*)xb + (long)m0 * 768, 768,
                 (const char*)wqkv + (long)oc0 * 768, 768, 6, A_lds, B_lds, acc);

    const int tid = threadIdx.x, wid = tid >> 6, lane = tid & 63;
    const int wm = (wid & 1) * 64, wn = (wid >> 1) * 64;
    const int col = lane & 15, quad = lane >> 4;
    #pragma unroll
    for (int i = 0; i < 4; ++i) {
        #pragma unroll
        for (int j = 0; j < 4; ++j) {
            #pragma unroll
            for (int r = 0; r < 4; ++r) {
                int m  = m0 + wm + i * 16 + quad * 4 + r;
                int oc = oc0 + wn + j * 16 + col;
                int b = m / NSP, n = m - b * NSP;
                float v = acc[i][j][r];
                if (oc < 256) {
                    qt[(long)m * NQK + oc] = f2b(v + qb[oc]);
                } else if (oc < 512) {
                    int o = oc - 256;
                    kb16[(long)m * NQK + o] = f2b(v + kb[o]);
                } else {
                    int o = oc - 512, h = o >> 7, d = o & 127;
                    vt[(((long)b * NHD + h) * NSP + n) * DVV + d] = f2b(v + vb[o]);
                }
            }
        }
    }
}

// ---------------- prep: vt -> vtT (bh, d, m) rows padded to 224 ----------
__global__ __launch_bounds__(256) void k_vtT(
    const u16* __restrict__ vt, u16* __restrict__ vtT)
{
    __shared__ u16 t[32][33];
    const int bh = blockIdx.z, d0 = blockIdx.y * 32, n0 = blockIdx.x * 32;
    const int tx = threadIdx.x & 31, ty = threadIdx.x >> 5;
    #pragma unroll
    for (int l = 0; l < 4; ++l) {
        int n = n0 + ty + 8 * l, d = d0 + tx;
        t[ty + 8 * l][tx] = (n < NSP) ? vt[((long)bh * NSP + n) * DVV + d] : (u16)0;
    }
    __syncthreads();
    #pragma unroll
    for (int l = 0; l < 4; ++l) {
        int d = d0 + ty + 8 * l, m = n0 + tx;
        vtT[((long)bh * DVV + d) * 224 + m] = t[tx][ty + 8 * l];
    }
}

// ---------------- K2: depthwise 3x3 conv, vectorized over 8 d ----------------
__global__ __launch_bounds__(256) void k_dwconv(
    const u16* __restrict__ vt, const u16* __restrict__ wpack,
    const float* __restrict__ vlb, u16* __restrict__ vlt)
{
    const int tid = threadIdx.x;
    const int dg = tid & 15;                 // d0 = dg*8
    const int nl = tid >> 4;                 // 16 n per block
    const int bh = blockIdx.y;
    const int n  = blockIdx.x * 16 + nl;
    if (n >= NSP) return;
    const int d0 = dg * 8;
    const int h  = bh & 7;
    const int y = n / RES, xx = n - y * RES;
    const long plane = (long)bh * NSP * DVV;
    float acc[8];
    #pragma unroll
    for (int t = 0; t < 8; ++t) acc[t] = vlb[h * DVV + d0 + t];
    const u16* wb = wpack + (h * 16 + dg) * 72;
    #pragma unroll
    for (int dy = -1; dy <= 1; ++dy) {
        int yy = y + dy;
        if (yy < 0 || yy >= RES) continue;
        #pragma unroll
        for (int dx = -1; dx <= 1; ++dx) {
            int xn = xx + dx;
            if (xn < 0 || xn >= RES) continue;
            int tap = (dy + 1) * 3 + dx + 1;
            bf16x8 v  = *(const bf16x8*)&vt[plane + (yy * RES + xn) * DVV + d0];
            bf16x8 wv = *(const bf16x8*)&wb[tap * 8];
            #pragma unroll
            for (int t = 0; t < 8; ++t)
                acc[t] += b2f((u16)wv[t]) * b2f((u16)v[t]);
        }
    }
    bf16x8 r;
    #pragma unroll
    for (int t = 0; t < 8; ++t) r[t] = (short)f2b(acc[t]);
    *(bf16x8*)&vlt[plane + (long)n * DVV + d0] = r;
}

// ---------------- K3: fused attention middle, 512 thr x 16-row strips ------
// grid 832: xcd = L&7, b = xcd + 8*(wq/13), strip = wq%13, n0 = strip*16.
// S: 128 rows x 224 u16 = 57,344 B + bmS 3,136 B -> 2 blocks/CU (16 waves).
__global__ __launch_bounds__(512, 4) void k_attn2(
    const u16* __restrict__ qt, const u16* __restrict__ kb16,
    const u16* __restrict__ vtT, const u16* __restrict__ vlt,
    const float* __restrict__ th1w, const float* __restrict__ th2w,
    const float* __restrict__ th2b, const float* __restrict__ biasmix,
    u16* __restrict__ ot)
{
    __shared__ u16 S[128 * SROW];
    __shared__ u16 bmS[8 * NSP];
    const int tid = threadIdx.x;
    const int L  = blockIdx.x;
    const int wq = L >> 3;
    const int b  = (L & 7) + ((wq / NSTRIP) << 3);
    const int n0 = (wq % NSTRIP) * 16;
    const int wid = tid >> 6, lane = tid & 63;
    const int l15 = lane & 15, lq8 = (lane >> 4) * 8;
    const int quad = lane >> 4, col = lane & 15;

    for (int i = tid; i < 8 * NSP; i += 512) bmS[i] = f2b(biasmix[i]);
    __syncthreads();

    // ---- phase 1: scores (MFMA) + th1 mix + bias, fused in registers ----
    {
        const long qrow = ((long)(b * NSP) + n0 + l15) * NQK;
        bf16x8 af[8];
        #pragma unroll
        for (int g = 0; g < 8; ++g)
            af[g] = *(const bf16x8*)&qt[qrow + g * 32 + lq8];
        #pragma unroll
        for (int jj = 0; jj < 2; ++jj) {
            const int j = wid + jj * 8;
            if (j >= 14) break;
            const long krow = ((long)(b * NSP) + j * 16 + l15) * NQK;
            f32x4 t[8];
            #pragma unroll
            for (int g = 0; g < 8; ++g) {
                bf16x8 bv = *(const bf16x8*)&kb16[krow + g * 32 + lq8];
                t[g] = __builtin_amdgcn_mfma_f32_16x16x32_bf16(
                    af[g], bv, (f32x4){0.f, 0.f, 0.f, 0.f}, 0, 0, 0);
            }
            const int m = j * 16 + col;
            const int ym = m / RES, xm = m - ym * RES;
            int offr[4];
            #pragma unroll
            for (int r = 0; r < 4; ++r) {
                int gn = n0 + quad * 4 + r;
                int yn = gn / RES, xn = gn - yn * RES;
                int off = abs(yn - ym) * RES + abs(xn - xm);
                offr[r] = (off > 195) ? 195 : off;   // garbage rows/cols only
            }
            #pragma unroll
            for (int h = 0; h < 8; ++h) {
                float o[4];
                #pragma unroll
                for (int r = 0; r < 4; ++r) o[r] = b2f(bmS[h * NSP + offr[r]]);
                #pragma unroll
                for (int g = 0; g < 8; ++g) {
                    const float w = th1w[h * 8 + g] * SCALE;  // SGPR
                    #pragma unroll
                    for (int r = 0; r < 4; ++r) o[r] += w * t[g][r];
                }
                #pragma unroll
                for (int r = 0; r < 4; ++r)
                    S[(h * 16 + quad * 4 + r) * SROW + m] = f2b(o[r]);
            }
        }
    }
    __syncthreads();

    // ---- phase 3: softmax, 4 rows per wave concurrently (16-lane groups) ----
    {
        const int c = lane & 15, rg = lane >> 4;
        #pragma unroll
        for (int it = 0; it < 4; ++it) {
            u16* row = &S[(wid * 16 + it * 4 + rg) * SROW];
            float v[13];
            #pragma unroll
            for (int k = 0; k < 12; ++k) v[k] = b2f(row[c + 16 * k]);
            v[12] = (c < 4) ? b2f(row[192 + c]) : -1e30f;
            float mx = v[0];
            #pragma unroll
            for (int k = 1; k < 13; ++k) mx = fmaxf(mx, v[k]);
            #pragma unroll
            for (int o = 1; o < 16; o <<= 1) mx = fmaxf(mx, __shfl_xor(mx, o));
            float sum = 0.f;
            #pragma unroll
            for (int k = 0; k < 13; ++k) { v[k] = __expf(v[k] - mx); sum += v[k]; }
            if (c >= 4) sum -= v[12];   // garbage lane contribution
            #pragma unroll
            for (int o = 1; o < 16; o <<= 1) sum += __shfl_xor(sum, o);
            float inv = 1.0f / sum;
            #pragma unroll
            for (int k = 0; k < 12; ++k) row[c + 16 * k] = f2b(v[k] * inv);
            if (c < 4) row[192 + c] = f2b(v[12] * inv);
        }
    }
    __syncthreads();

    // ---- phase 4: th2 mix (+bias), zero pad m in [196,224), paired u32 ----
    {
        for (int p = tid; p < 16 * 112; p += 512) {
            const int nl = p / 112, kp = p - nl * 112;
            const int m0 = kp * 2;
            if (m0 >= NSP) {
                #pragma unroll
                for (int h = 0; h < 8; ++h)
                    *(u32*)&S[(h * 16 + nl) * SROW + m0] = 0u;
                continue;
            }
            float s0[8], s1[8];
            #pragma unroll
            for (int g = 0; g < 8; ++g) {
                u32 v = *(const u32*)&S[(g * 16 + nl) * SROW + m0];
                s0[g] = b2f((u16)(v & 0xffff));
                s1[g] = b2f((u16)(v >> 16));
            }
            #pragma unroll
            for (int h = 0; h < 8; ++h) {
                float o0 = th2b[h], o1 = th2b[h];
                #pragma unroll
                for (int g = 0; g < 8; ++g) {
                    const float w = th2w[h * 8 + g];   // SGPR
                    o0 += w * s0[g];
                    o1 += w * s1[g];
                }
                *(u32*)&S[(h * 16 + nl) * SROW + m0] =
                    (u32)f2b(o0) | ((u32)f2b(o1) << 16);
            }
        }
    }
    __syncthreads();

    // ---- phase 5: O = P @ V + vlocal, ReLU (one head per wave, full M) ----
    {
        const int h = wid;
        const long vrow = (long)(b * NHD + h) * DVV;
        f32x4 acc[8];
        #pragma unroll
        for (int df = 0; df < 8; ++df) acc[df] = (f32x4){0.f, 0.f, 0.f, 0.f};
        for (int kc = 0; kc < 7; ++kc) {
            bf16x8 a0 = *(const bf16x8*)&S[(h * 16 + l15) * SROW + kc * 32 + lq8];
            #pragma unroll
            for (int df = 0; df < 8; ++df) {
                bf16x8 bv = *(const bf16x8*)&vtT[(vrow + df * 16 + l15) * 224 + kc * 32 + lq8];
                acc[df] = __builtin_amdgcn_mfma_f32_16x16x32_bf16(a0, bv, acc[df], 0, 0, 0);
            }
        }
        const long lbase = (long)(b * NHD + h) * NSP;
        #pragma unroll
        for (int df = 0; df < 8; ++df) {
            #pragma unroll
            for (int r = 0; r < 4; ++r) {
                int n = n0 + quad * 4 + r;
                int d = df * 16 + col;
                if (n < NSP) {
                    float v = acc[df][r] + b2f(vlt[(lbase + n) * DVV + d]);
                    v = fmaxf(v, 0.f);
                    ot[((long)(b * NSP + n)) * 1024 + h * DVV + d] = f2b(v);
                }
            }
        }
    }
}

// ---------------- K5: output projection (MFMA, BK=64), 128oc x 64m ----------
// 24 staging segments (2 subs x (8 A + 4 B)); wave w stages segs 6w..6w+5.
__global__ __launch_bounds__(256) void k_proj(
    const u16* __restrict__ pwb, const u16* __restrict__ ot,
    const float* __restrict__ projb, float* __restrict__ outp)
{
    __shared__ u16 A_lds[8192];   // 2 x 128 rows x 32
    __shared__ u16 B_lds[4096];   // 2 x  64 rows x 32
    const int tid = threadIdx.x, wid = tid >> 6, lane = tid & 63;
    const int lrow = lane >> 2, lcb = (lane & 3) << 4;
    const int m0 = blockIdx.x * 64, oc0 = blockIdx.y * 128;
    const int wm = (wid & 1) * 64, wn = (wid >> 1) * 32;
    const int l15 = lane & 15, lq8 = (lane >> 4) * 8;

    const char* gp[6];
    u16* lp[6];
    #pragma unroll
    for (int t = 0; t < 6; ++t) {
        int s = wid * 6 + t;            // 0..23
        int sub = s / 12, s12 = s - sub * 12;
        if (s12 < 8) {
            gp[t] = (const char*)pwb + (long)(oc0 + s12 * 16 + lrow) * 2048 + lcb + sub * 64;
            lp[t] = A_lds + sub * 4096 + s12 * 512;
        } else {
            gp[t] = (const char*)ot + (long)(m0 + (s12 - 8) * 16 + lrow) * 2048 + lcb + sub * 64;
            lp[t] = B_lds + sub * 2048 + (s12 - 8) * 512;
        }
    }

    f32x4 acc[4][2];
    #pragma unroll
    for (int i = 0; i < 4; ++i)
        #pragma unroll
        for (int j = 0; j < 2; ++j) acc[i][j] = (f32x4){0.f, 0.f, 0.f, 0.f};

    for (int kk = 0; kk < 16; ++kk) {
        #pragma unroll
        for (int t = 0; t < 6; ++t) { gld16(gp[t], lp[t]); gp[t] += 128; }
        __syncthreads();
        #pragma unroll
        for (int s = 0; s < 2; ++s) {
            bf16x8 af[4], bfr[2];
            #pragma unroll
            for (int i = 0; i < 4; ++i)
                af[i] = *(const bf16x8*)&A_lds[s * 4096 + (wm + i * 16 + l15) * 32 + lq8];
            #pragma unroll
            for (int j = 0; j < 2; ++j)
                bfr[j] = *(const bf16x8*)&B_lds[s * 2048 + (wn + j * 16 + l15) * 32 + lq8];
            #pragma unroll
            for (int i = 0; i < 4; ++i)
                #pragma unroll
                for (int j = 0; j < 2; ++j)
                    acc[i][j] = __builtin_amdgcn_mfma_f32_16x16x32_bf16(
                        af[i], bfr[j], acc[i][j], 0, 0, 0);
        }
        __syncthreads();
    }

    const int col = lane & 15, quad = lane >> 4;
    #pragma unroll
    for (int i = 0; i < 4; ++i) {
        #pragma unroll
        for (int j = 0; j < 2; ++j) {
            #pragma unroll
            for (int r = 0; r < 4; ++r) {
                int oc = oc0 + wm + i * 16 + quad * 4 + r;
                int mg = m0 + wn + j * 16 + col;
                int b = mg / NSP, n = mg - b * NSP;
                outp[((long)b * DIM + oc) * NSP + n] = acc[i][j][r] + projb[oc];
            }
        }
    }
}

extern "C" void kernel_launch(void* const* d_in, const int* in_sizes, int n_in,
                              void* d_out, int out_size, void* d_ws, size_t ws_size,
                              hipStream_t stream) {
    const float* x        = (const float*)d_in[0];
    const float* qw       = (const float*)d_in[1];
    const float* qb       = (const float*)d_in[2];
    const float* kw       = (const float*)d_in[3];
    const float* kb       = (const float*)d_in[4];
    const float* vw       = (const float*)d_in[5];
    const float* vb       = (const float*)d_in[6];
    const float* vlw      = (const float*)d_in[7];
    const float* vlb      = (const float*)d_in[8];
    const float* th1w     = (const float*)d_in[9];
    const float* th1b     = (const float*)d_in[10];
    const float* th2w     = (const float*)d_in[11];
    const float* th2b     = (const float*)d_in[12];
    const float* projw    = (const float*)d_in[13];
    const float* projb    = (const float*)d_in[14];
    const float* bias_seg = (const float*)d_in[15];
    float* outp = (float*)d_out;

    // workspace layout (bytes, 16B aligned)
    char* w = (char*)d_ws;
    u16* xb      = (u16*)(w);                 //  9,633,792
    u16* wqkv    = (u16*)(w + 9633792);       //  1,179,648
    u16* pwb     = (u16*)(w + 10813440);      //    786,432
    u16* wpack   = (u16*)(w + 11599872);      //     18,432
    float* bmix  = (float*)(w + 11618304);    //      6,400
    u16* qt      = (u16*)(w + 11624704);      //  6,455,296 (12608 rows x 256)
    u16* kb16    = (u16*)(w + 18080000);      //  6,455,296
    u16* vt      = (u16*)(w + 24535296);      // 25,690,112
    u16* vtT     = (u16*)(w + 50225408);      // 29,360,128
    u16* ot      = (u16*)(w + 79585536);      // 25,690,112
    u16* vlt     = (u16*)(w + 105275648);     // 25,690,112
    // total 130,965,760 B

    k_prep<<<dim3(9259), 256, 0, stream>>>(qw, kw, vw, projw, th1w, th1b,
                                           bias_seg, vlw, x, wqkv, pwb, bmix,
                                           wpack, xb);
    k_qkv<<<dim3(98, 12), 256, 0, stream>>>(xb, wqkv, qb, kb, vb, qt, kb16, vt);
    k_vtT<<<dim3(7, 4, 512), 256, 0, stream>>>(vt, vtT);
    k_dwconv<<<dim3(13, 512), 256, 0, stream>>>(vt, wpack, vlb, vlt);
    k_attn2<<<dim3(NSTRIP * 64), 512, 0, stream>>>(qt, kb16, vtT, vlt, th1w, th2w,
                                                   th2b, bmix, ot);
    k_proj<<<dim3(196, 3), 256, 0, stream>>>(pwb, ot, projb, outp);
}